// Round 15
// baseline (148.243 us; speedup 1.0000x reference)
//
#include <hip/hip_runtime.h>
#include <hip/hip_bf16.h>

#define BATCH 65536
#define DIN   128
#define DH    512
#define DOUT  128
#define ROWS  64

typedef __attribute__((ext_vector_type(4))) float f32x4;
typedef __attribute__((ext_vector_type(8))) short s16x8;

__device__ __forceinline__ ushort f32_to_bf16_rn(float f) {
    uint32_t u = __float_as_uint(f);
    uint32_t r = (u + 0x7FFFu + ((u >> 16) & 1u)) >> 16;
    return (ushort)r;
}
__device__ __forceinline__ float bf16_to_f32(ushort h) {
    return __uint_as_float(((uint32_t)h) << 16);
}
__device__ __forceinline__ f32x4 mfma16(s16x8 a, s16x8 b, f32x4 c) {
    return __builtin_amdgcn_mfma_f32_16x16x32_bf16(a, b, c, 0, 0, 0);
}
// two f32x4 -> one s16x8 (plain bf16 RN; tolerance 8.0 >> bf16 GEMM error)
__device__ __forceinline__ s16x8 cvt8(f32x4 v0, f32x4 v1) {
    s16x8 r;
#pragma unroll
    for (int j = 0; j < 4; ++j) r[j] = (short)f32_to_bf16_rn(v0[j]);
#pragma unroll
    for (int j = 0; j < 4; ++j) r[4 + j] = (short)f32_to_bf16_rn(v1[j]);
    return r;
}

// ---------------------------------------------------------------------------
// prep: blk0 softmax(a); blk1..64 split B,C -> bf16 frag-linear. [verified]
// perm[(f*64+lane)*8+j] = M[k][col], k = ks*32+(lane>>4)*8+j,
// col = cg*16+(lane&15). B: f=cg*4+ks (cg<32). C: f=cg*16+ksg (cg<8,ksg<16).
// ---------------------------------------------------------------------------
__global__ void prep_kernel(const float* __restrict__ a,
                            const float* __restrict__ b,
                            const float* __restrict__ c,
                            float* __restrict__ decay,
                            ushort* __restrict__ bhi,
                            ushort* __restrict__ chi)
{
    const int t = threadIdx.x;
    if (blockIdx.x == 0) {
        __shared__ float red[256];
        float v0 = a[t], v1 = a[t + 256];
        red[t] = fmaxf(v0, v1);
        __syncthreads();
        for (int s = 128; s > 0; s >>= 1) {
            if (t < s) red[t] = fmaxf(red[t], red[t + s]);
            __syncthreads();
        }
        float M = red[0];
        __syncthreads();
        float e0 = expf(v0 - M), e1 = expf(v1 - M);
        red[t] = e0 + e1;
        __syncthreads();
        for (int s = 128; s > 0; s >>= 1) {
            if (t < s) red[t] += red[t + s];
            __syncthreads();
        }
        float S = red[0];
        decay[t]       = e0 / S;
        decay[t + 256] = e1 / S;
    } else {
        const int p = (blockIdx.x - 1) * 256 + t;
        const int mtx = p >> 13;
        const int q = p & 8191;
        const int f = q >> 6;
        const int l = q & 63;
        s16x8 hi;
        if (mtx == 0) {
            const int cg = f >> 2, ks = f & 3;
            const int col = cg * 16 + (l & 15);
            const int kbase = ks * 32 + (l >> 4) * 8;
#pragma unroll
            for (int j = 0; j < 8; ++j)
                hi[j] = (short)f32_to_bf16_rn(b[(size_t)(kbase + j) * DH + col]);
            *(s16x8*)(bhi + (size_t)q * 8) = hi;
        } else {
            const int cg = f >> 4, ks = f & 15;
            const int col = cg * 16 + (l & 15);
            const int kbase = ks * 32 + (l >> 4) * 8;
#pragma unroll
            for (int j = 0; j < 8; ++j)
                hi[j] = (short)f32_to_bf16_rn(c[(size_t)(kbase + j) * DOUT + col]);
            *(s16x8*)(chi + (size_t)q * 8) = hi;
        }
    }
}

// ---------------------------------------------------------------------------
// fused v10: wave-stripe, ZERO barriers. Block = 64 rows, 4 waves; wave w
// owns rows [row0+w*16, +16) end-to-end; all LDS is wave-private:
//   A_w = bf16(u stripe) 4KB (coalesced 128B/lane staging, swizzled)
//   X_w dbuf 2x2KB.
// Per 64-col chunk ct: x prefetch (quarter-wave 64B, v9's pattern) ->
//   GEMM1 (u@B: 4 ks x {1 ds_read, 4 B-frag 1KB L2 loads, 4 MFMA}) ->
//   epilogue (xn = acc1+dv*x store; X = bf16(xn) -> wave LDS) ->
//   GEMM2 (X@C: 2 ks2 x {1 ds_read, 8 C-frag loads, 8 MFMA}) -> acc2.
// Same-wave LDS WAR handled by dbuf + in-order lgkm; waves fully
// independent -> 16-20 uncorrelated streams/CU (v9 had 4 correlated).
// ---------------------------------------------------------------------------
__global__ __launch_bounds__(256, 4)
void rnn_fused(const float* __restrict__ u, const float* __restrict__ x,
               const float* __restrict__ decay,
               const ushort* __restrict__ bhi, const ushort* __restrict__ chi,
               float* __restrict__ xn, float* __restrict__ out)
{
    __shared__ __align__(16) char smem[32768];

    const int t = threadIdx.x;
    const int lane = t & 63, w = t >> 6;
    const int cl = lane & 15, hk = lane >> 4;
    const int row0 = blockIdx.x * ROWS;
    const int wrow = row0 + w * 16;          // wave's global row base

    char* Aw = smem + w * 4096;              // [16][128] bf16, swz, 4KB
    char* Xb = smem + 16384 + w * 4096;      // 2 x [16][64] bf16, swz, 2KB ea

    {   // stage A: wave w loads its own u stripe; lane: row lr, 32 cols
        const int lr = lane >> 2;
        const int cb = (lane & 3) * 32;
        const float* src = u + (size_t)(wrow + lr) * DIN + cb;
#pragma unroll
        for (int i = 0; i < 4; ++i) {
            f32x4 v0 = *(const f32x4*)(src + i * 8);
            f32x4 v1 = *(const f32x4*)(src + i * 8 + 4);
            const int byte = (lr * 256 + (cb + i * 8) * 2) ^ ((lr & 7) << 4);
            *(s16x8*)(Aw + byte) = cvt8(v0, v1);
        }
    }
    // no barrier: A_w written and read by the same wave only

    f32x4 acc2[8];
#pragma unroll
    for (int nf2 = 0; nf2 < 8; ++nf2) acc2[nf2] = (f32x4){0.f, 0.f, 0.f, 0.f};

    for (int ct = 0; ct < 8; ++ct) {
        char* Xh = Xb + (ct & 1) * 2048;     // [16][64] bf16, swz

        // ---- x + decay prefetch for epilogue (C/D pattern, 4 col-frags)
        float xv[4][4], dv[4];
#pragma unroll
        for (int nf = 0; nf < 4; ++nf) {
            const int col = ct * 64 + nf * 16 + cl;
            dv[nf] = decay[col];
#pragma unroll
            for (int j = 0; j < 4; ++j)
                xv[nf][j] = x[(size_t)(wrow + 4 * hk + j) * DH + col];
        }

        // ---- GEMM1: acc1 = u-stripe @ B-chunk (16 rows x 64 cols, K=128)
        f32x4 acc1[4];
#pragma unroll
        for (int nf = 0; nf < 4; ++nf) acc1[nf] = (f32x4){0.f, 0.f, 0.f, 0.f};
#pragma unroll
        for (int ks = 0; ks < 4; ++ks) {
            const int ko = ks * 32 + hk * 8;
            const int abyte = (cl * 256 + ko * 2) ^ ((cl & 7) << 4);
            s16x8 ah = *(const s16x8*)(Aw + abyte);
#pragma unroll
            for (int nf = 0; nf < 4; ++nf) {
                const size_t fB = (size_t)((ct * 4 + nf) * 4 + ks) * 512 + lane * 8;
                s16x8 bh = *(const s16x8*)(bhi + fB);
                acc1[nf] = mfma16(ah, bh, acc1[nf]);
            }
        }

        // ---- epilogue: xn = acc1 + dv*x (store); X = bf16(xn) -> wave LDS
#pragma unroll
        for (int nf = 0; nf < 4; ++nf) {
            const int col = ct * 64 + nf * 16 + cl;
#pragma unroll
            for (int j = 0; j < 4; ++j) {
                const int lr = 4 * hk + j;
                const float v = acc1[nf][j] + dv[nf] * xv[nf][j];
                xn[(size_t)(wrow + lr) * DH + col] = v;
                const int cb = (lr * 128 + (nf * 16 + cl) * 2) ^ ((lr & 7) << 4);
                *(ushort*)(Xh + cb) = f32_to_bf16_rn(v);
            }
        }
        // no barrier: X_w read by the same wave only (lgkm dep ordering)

        // ---- GEMM2: acc2 += X @ C-chunk (16 rows x 128 cols, K=64)
#pragma unroll
        for (int ks2 = 0; ks2 < 2; ++ks2) {
            const int xbyte = (cl * 128 + (ks2 * 32 + hk * 8) * 2) ^ ((cl & 7) << 4);
            s16x8 xh = *(const s16x8*)(Xh + xbyte);
            const int ksg = ct * 2 + ks2;
#pragma unroll
            for (int nf2 = 0; nf2 < 8; ++nf2) {
                const size_t fC = (size_t)(nf2 * 16 + ksg) * 512 + lane * 8;
                s16x8 ch = *(const s16x8*)(chi + fC);
                acc2[nf2] = mfma16(xh, ch, acc2[nf2]);
            }
        }
    }

    // ---- store out stripe [16 x 128]
#pragma unroll
    for (int nf2 = 0; nf2 < 8; ++nf2) {
        const int ocol = nf2 * 16 + cl;
#pragma unroll
        for (int j = 0; j < 4; ++j)
            out[(size_t)(wrow + 4 * hk + j) * DOUT + ocol] = acc2[nf2][j];
    }
}

extern "C" void kernel_launch(void* const* d_in, const int* in_sizes, int n_in,
                              void* d_out, int out_size, void* d_ws, size_t ws_size,
                              hipStream_t stream)
{
    const float* x = (const float*)d_in[0];
    const float* u = (const float*)d_in[1];
    const float* a = (const float*)d_in[2];
    const float* b = (const float*)d_in[3];
    const float* c = (const float*)d_in[4];

    float* xn  = (float*)d_out;                       // [BATCH][DH]
    float* out = xn + (size_t)BATCH * DH;             // [BATCH][DOUT]

    char* ws = (char*)d_ws;
    float*  decay = (float*)ws;                       // 512 f32
    ushort* bhi = (ushort*)(ws + 4096);               // 128KB frag-linear B
    ushort* chi = bhi + 128 * 512;                    // 128KB frag-linear C

    prep_kernel<<<dim3(65), dim3(256), 0, stream>>>(a, b, c, decay, bhi, chi);
    rnn_fused<<<dim3(BATCH / ROWS), dim3(256), 0, stream>>>(u, x, decay, bhi, chi, xn, out);
}

// Round 16
// 116.957 us; speedup vs baseline: 1.2675x; 1.2675x over previous
//
#include <hip/hip_runtime.h>
#include <hip/hip_bf16.h>

#define BATCH 65536
#define DIN   128
#define DH    512
#define DOUT  128
#define ROWS  32

typedef __attribute__((ext_vector_type(4))) float f32x4;
typedef __attribute__((ext_vector_type(8))) short s16x8;

__device__ __forceinline__ ushort f32_to_bf16_rn(float f) {
    uint32_t u = __float_as_uint(f);
    uint32_t r = (u + 0x7FFFu + ((u >> 16) & 1u)) >> 16;
    return (ushort)r;
}
__device__ __forceinline__ float bf16_to_f32(ushort h) {
    return __uint_as_float(((uint32_t)h) << 16);
}
__device__ __forceinline__ f32x4 mfma16(s16x8 a, s16x8 b, f32x4 c) {
    return __builtin_amdgcn_mfma_f32_16x16x32_bf16(a, b, c, 0, 0, 0);
}
// two f32x4 -> one s16x8 (plain bf16 RN; tolerance 8.0 >> bf16 GEMM error)
__device__ __forceinline__ s16x8 cvt8(f32x4 v0, f32x4 v1) {
    s16x8 r;
#pragma unroll
    for (int j = 0; j < 4; ++j) r[j] = (short)f32_to_bf16_rn(v0[j]);
#pragma unroll
    for (int j = 0; j < 4; ++j) r[4 + j] = (short)f32_to_bf16_rn(v1[j]);
    return r;
}

// ---------------------------------------------------------------------------
// prep: blk0 softmax(a); blk1..64 split B,C -> bf16 frag-linear. [verified]
// perm[(f*64+lane)*8+j] = M[k][col], k = ks*32+(lane>>4)*8+j,
// col = cg*16+(lane&15). B: f=cg*4+ks (cg<32). C: f=cg*16+ksg (cg<8,ksg<16).
// ---------------------------------------------------------------------------
__global__ void prep_kernel(const float* __restrict__ a,
                            const float* __restrict__ b,
                            const float* __restrict__ c,
                            float* __restrict__ decay,
                            ushort* __restrict__ bhi,
                            ushort* __restrict__ chi)
{
    const int t = threadIdx.x;
    if (blockIdx.x == 0) {
        __shared__ float red[256];
        float v0 = a[t], v1 = a[t + 256];
        red[t] = fmaxf(v0, v1);
        __syncthreads();
        for (int s = 128; s > 0; s >>= 1) {
            if (t < s) red[t] = fmaxf(red[t], red[t + s]);
            __syncthreads();
        }
        float M = red[0];
        __syncthreads();
        float e0 = expf(v0 - M), e1 = expf(v1 - M);
        red[t] = e0 + e1;
        __syncthreads();
        for (int s = 128; s > 0; s >>= 1) {
            if (t < s) red[t] += red[t + s];
            __syncthreads();
        }
        float S = red[0];
        decay[t]       = e0 / S;
        decay[t + 256] = e1 / S;
    } else {
        const int p = (blockIdx.x - 1) * 256 + t;
        const int mtx = p >> 13;
        const int q = p & 8191;
        const int f = q >> 6;
        const int l = q & 63;
        s16x8 hi;
        if (mtx == 0) {
            const int cg = f >> 2, ks = f & 3;
            const int col = cg * 16 + (l & 15);
            const int kbase = ks * 32 + (l >> 4) * 8;
#pragma unroll
            for (int j = 0; j < 8; ++j)
                hi[j] = (short)f32_to_bf16_rn(b[(size_t)(kbase + j) * DH + col]);
            *(s16x8*)(bhi + (size_t)q * 8) = hi;
        } else {
            const int cg = f >> 4, ks = f & 15;
            const int col = cg * 16 + (l & 15);
            const int kbase = ks * 32 + (l >> 4) * 8;
#pragma unroll
            for (int j = 0; j < 8; ++j)
                hi[j] = (short)f32_to_bf16_rn(c[(size_t)(kbase + j) * DOUT + col]);
            *(s16x8*)(chi + (size_t)q * 8) = hi;
        }
    }
}

// ---------------------------------------------------------------------------
// fused v11: v9 structure + LDS-transposed COALESCED epilogue (R4-k1's
// 2.95 TB/s pattern). Block = 32 rows, 4 waves, 8 chunks x 64 cols.
// LDS 20.5KB single-buffered (A 8KB swz + T [32][68]f32 8.5KB + X 4KB swz):
// every T/X WAR is separated by >=1 barrier (see per-chunk flow).
// Per chunk:  GEMM1 (u@B, acc1) ; T<-acc1 (scalar LDS, 2-way free) ;
//   prefetch x[ct+1] (f32x4 coalesced regs) ; bar1 ;
//   coalesced: v = T(b128) + dv*x ; xn store f32x4 ; X <- bf16(v) (b128) ;
//   bar2 ; GEMM2 (X@C, acc2). 16 barriers/block, all traffic >=1KB/instr.
// ---------------------------------------------------------------------------
__global__ __launch_bounds__(256, 6)
void rnn_fused(const float* __restrict__ u, const float* __restrict__ x,
               const float* __restrict__ decay,
               const ushort* __restrict__ bhi, const ushort* __restrict__ chi,
               float* __restrict__ xn, float* __restrict__ out)
{
    __shared__ __align__(16) char smem[20896];
    ushort* Ah = (ushort*)smem;              // [32][128] bf16, swz, 8KB
    float*  T  = (float*)(smem + 8192);      // [32][68] f32, 8704B
    char*   Xh = smem + 16896;               // [32][64] bf16, swz, 4KB

    const int t = threadIdx.x;
    const int lane = t & 63, wc = t >> 6;
    const int cl = lane & 15, hk = lane >> 4;
    const int row0 = blockIdx.x * ROWS;

    {   // stage A: u[32][128] f32 -> bf16 swizzled; 64B/thread coalesced
        const int r = t >> 3;
        const int kb = (t & 7) * 2;
#pragma unroll
        for (int i = 0; i < 2; ++i) {
            const float* src = u + (size_t)(row0 + r) * DIN + (kb + i) * 8;
            f32x4 v0 = *(const f32x4*)src;
            f32x4 v1 = *(const f32x4*)(src + 4);
            const int byte = (r * 256 + (kb + i) * 16) ^ ((r & 7) << 4);
            *(s16x8*)((char*)Ah + byte) = cvt8(v0, v1);
        }
    }

    // coalesced-domain geometry: thread = (row r2, 8 cols at c0) of the
    // 32x64 chunk tile; consecutive threads cover consecutive 32B.
    const int r2 = t >> 3;
    const int c0 = (t & 7) * 8;
    const float* xrow = x + (size_t)(row0 + r2) * DH + c0;

    // prologue: prefetch chunk-0 x
    f32x4 xc0 = *(const f32x4*)xrow;
    f32x4 xc1 = *(const f32x4*)(xrow + 4);
    f32x4 xr0, xr1;

    __syncthreads();   // A visible

    f32x4 acc2[2][2];
#pragma unroll
    for (int mf = 0; mf < 2; ++mf)
#pragma unroll
        for (int nf = 0; nf < 2; ++nf)
            acc2[mf][nf] = (f32x4){0.f, 0.f, 0.f, 0.f};

    for (int ct = 0; ct < 8; ++ct) {
        // ---- GEMM1: acc1 = u @ B-chunk; wave tile 32 rows x 16 cols
        f32x4 acc1[2];
        acc1[0] = (f32x4){0.f, 0.f, 0.f, 0.f};
        acc1[1] = (f32x4){0.f, 0.f, 0.f, 0.f};
#pragma unroll
        for (int ks = 0; ks < 4; ++ks) {
            const int ko = ks * 32 + hk * 8;
            s16x8 ah[2];
#pragma unroll
            for (int mf = 0; mf < 2; ++mf) {
                const int r = mf * 16 + cl;
                const int byte = (r * 256 + ko * 2) ^ ((r & 7) << 4);
                ah[mf] = *(const s16x8*)((const char*)Ah + byte);
            }
            const size_t fB = (size_t)((ct * 4 + wc) * 4 + ks) * 512 + lane * 8;
            s16x8 bh = *(const s16x8*)(bhi + fB);
#pragma unroll
            for (int mf = 0; mf < 2; ++mf) acc1[mf] = mfma16(ah[mf], bh, acc1[mf]);
        }

        // ---- T <- acc1 (C/D lanes -> padded T; 2 lanes/bank = free).
        // WAR safe: T readers of chunk ct-1 finished before bar2(ct-1).
#pragma unroll
        for (int mf = 0; mf < 2; ++mf)
#pragma unroll
            for (int j = 0; j < 4; ++j)
                T[(mf * 16 + 4 * hk + j) * 68 + wc * 16 + cl] = acc1[mf][j];

        // ---- prefetch next chunk's x (coalesced, stays in flight)
        if (ct < 7) {
            xr0 = *(const f32x4*)(xrow + (ct + 1) * 64);
            xr1 = *(const f32x4*)(xrow + (ct + 1) * 64 + 4);
        }

        __syncthreads();   // bar1: T visible; X WAR (GEMM2(ct-1) done)

        // ---- coalesced epilogue: v = T + dv*x; xn f32x4 store; X <- bf16(v)
        {
            const f32x4 t0 = *(const f32x4*)&T[r2 * 68 + c0];
            const f32x4 t1 = *(const f32x4*)&T[r2 * 68 + c0 + 4];
            const f32x4 d0 = *(const f32x4*)&decay[ct * 64 + c0];
            const f32x4 d1 = *(const f32x4*)&decay[ct * 64 + c0 + 4];
            const f32x4 v0 = t0 + d0 * xc0;
            const f32x4 v1 = t1 + d1 * xc1;
            float* dst = xn + (size_t)(row0 + r2) * DH + ct * 64 + c0;
            *(f32x4*)dst       = v0;
            *(f32x4*)(dst + 4) = v1;
            const int xbyte = (r2 * 128 + c0 * 2) ^ ((r2 & 7) << 4);
            *(s16x8*)(Xh + xbyte) = cvt8(v0, v1);
        }

        __syncthreads();   // bar2: X visible; T WAR (next T-write after this)

        // ---- GEMM2: acc2 += X @ C-chunk; wave 32 rows x 32 cols, K=64
#pragma unroll
        for (int ks2 = 0; ks2 < 2; ++ks2) {
            const int ko = ks2 * 32 + hk * 8;
            s16x8 ah2[2];
#pragma unroll
            for (int mf = 0; mf < 2; ++mf) {
                const int r = mf * 16 + cl;
                const int byte = (r * 128 + ko * 2) ^ ((r & 7) << 4);
                ah2[mf] = *(const s16x8*)((const char*)Xh + byte);
            }
            const int ksg = ct * 2 + ks2;
#pragma unroll
            for (int nf = 0; nf < 2; ++nf) {
                const size_t fC = (size_t)((wc * 2 + nf) * 16 + ksg) * 512 + lane * 8;
                s16x8 ch = *(const s16x8*)(chi + fC);
#pragma unroll
                for (int mf = 0; mf < 2; ++mf)
                    acc2[mf][nf] = mfma16(ah2[mf], ch, acc2[mf][nf]);
            }
        }

        // rotate x prefetch
        xc0 = xr0;
        xc1 = xr1;
    }

    // ---- final: store out[32 x 128]; wave covers cols [wc*32, +32)
#pragma unroll
    for (int nf = 0; nf < 2; ++nf) {
        const int ocol = wc * 32 + nf * 16 + cl;
#pragma unroll
        for (int mf = 0; mf < 2; ++mf) {
#pragma unroll
            for (int j = 0; j < 4; ++j) {
                const int rl = mf * 16 + 4 * hk + j;
                out[(size_t)(row0 + rl) * DOUT + ocol] = acc2[mf][nf][j];
            }
        }
    }
}

extern "C" void kernel_launch(void* const* d_in, const int* in_sizes, int n_in,
                              void* d_out, int out_size, void* d_ws, size_t ws_size,
                              hipStream_t stream)
{
    const float* x = (const float*)d_in[0];
    const float* u = (const float*)d_in[1];
    const float* a = (const float*)d_in[2];
    const float* b = (const float*)d_in[3];
    const float* c = (const float*)d_in[4];

    float* xn  = (float*)d_out;                       // [BATCH][DH]
    float* out = xn + (size_t)BATCH * DH;             // [BATCH][DOUT]

    char* ws = (char*)d_ws;
    float*  decay = (float*)ws;                       // 512 f32
    ushort* bhi = (ushort*)(ws + 4096);               // 128KB frag-linear B
    ushort* chi = bhi + 128 * 512;                    // 128KB frag-linear C

    prep_kernel<<<dim3(65), dim3(256), 0, stream>>>(a, b, c, decay, bhi, chi);
    rnn_fused<<<dim3(BATCH / ROWS), dim3(256), 0, stream>>>(u, x, decay, bhi, chi, xn, out);
}

// Round 17
// 103.341 us; speedup vs baseline: 1.4345x; 1.1318x over previous
//
#include <hip/hip_runtime.h>
#include <hip/hip_bf16.h>

#define BATCH 65536
#define DIN   128
#define DH    512
#define DOUT  128
#define ROWS  32

typedef __attribute__((ext_vector_type(4))) float f32x4;
typedef __attribute__((ext_vector_type(8))) short s16x8;

__device__ __forceinline__ ushort f32_to_bf16_rn(float f) {
    uint32_t u = __float_as_uint(f);
    uint32_t r = (u + 0x7FFFu + ((u >> 16) & 1u)) >> 16;
    return (ushort)r;
}
__device__ __forceinline__ float bf16_to_f32(ushort h) {
    return __uint_as_float(((uint32_t)h) << 16);
}
__device__ __forceinline__ f32x4 mfma16(s16x8 a, s16x8 b, f32x4 c) {
    return __builtin_amdgcn_mfma_f32_16x16x32_bf16(a, b, c, 0, 0, 0);
}
// two f32x4 -> one s16x8 (plain bf16 RN; tolerance 8.0 >> bf16 GEMM error)
__device__ __forceinline__ s16x8 cvt8(f32x4 v0, f32x4 v1) {
    s16x8 r;
#pragma unroll
    for (int j = 0; j < 4; ++j) r[j] = (short)f32_to_bf16_rn(v0[j]);
#pragma unroll
    for (int j = 0; j < 4; ++j) r[4 + j] = (short)f32_to_bf16_rn(v1[j]);
    return r;
}

// ---------------------------------------------------------------------------
// prep: blk0 softmax(a); blk1..64 split B,C -> bf16 frag-linear. [verified]
// perm[(f*64+lane)*8+j] = M[k][col], k = ks*32+(lane>>4)*8+j,
// col = cg*16+(lane&15). B: f=cg*4+ks (cg<32). C: f=cg*16+ksg (cg<8,ksg<16).
// ---------------------------------------------------------------------------
__global__ void prep_kernel(const float* __restrict__ a,
                            const float* __restrict__ b,
                            const float* __restrict__ c,
                            float* __restrict__ decay,
                            ushort* __restrict__ bhi,
                            ushort* __restrict__ chi)
{
    const int t = threadIdx.x;
    if (blockIdx.x == 0) {
        __shared__ float red[256];
        float v0 = a[t], v1 = a[t + 256];
        red[t] = fmaxf(v0, v1);
        __syncthreads();
        for (int s = 128; s > 0; s >>= 1) {
            if (t < s) red[t] = fmaxf(red[t], red[t + s]);
            __syncthreads();
        }
        float M = red[0];
        __syncthreads();
        float e0 = expf(v0 - M), e1 = expf(v1 - M);
        red[t] = e0 + e1;
        __syncthreads();
        for (int s = 128; s > 0; s >>= 1) {
            if (t < s) red[t] += red[t + s];
            __syncthreads();
        }
        float S = red[0];
        decay[t]       = e0 / S;
        decay[t + 256] = e1 / S;
    } else {
        const int p = (blockIdx.x - 1) * 256 + t;
        const int mtx = p >> 13;
        const int q = p & 8191;
        const int f = q >> 6;
        const int l = q & 63;
        s16x8 hi;
        if (mtx == 0) {
            const int cg = f >> 2, ks = f & 3;
            const int col = cg * 16 + (l & 15);
            const int kbase = ks * 32 + (l >> 4) * 8;
#pragma unroll
            for (int j = 0; j < 8; ++j)
                hi[j] = (short)f32_to_bf16_rn(b[(size_t)(kbase + j) * DH + col]);
            *(s16x8*)(bhi + (size_t)q * 8) = hi;
        } else {
            const int cg = f >> 4, ks = f & 15;
            const int col = cg * 16 + (l & 15);
            const int kbase = ks * 32 + (l >> 4) * 8;
#pragma unroll
            for (int j = 0; j < 8; ++j)
                hi[j] = (short)f32_to_bf16_rn(c[(size_t)(kbase + j) * DOUT + col]);
            *(s16x8*)(chi + (size_t)q * 8) = hi;
        }
    }
}

// ---------------------------------------------------------------------------
// fused v12: v9 + explicit register-pipelined fragments, 1 barrier/chunk.
// Block = 32 rows, 4 waves, 8 chunks x 64 cols. LDS 16KB (A 8KB + X dbuf
// 2x4KB). Per chunk:
//   [cF = C(ct) loads issued FIRST]  (covered by GEMM1+epilogue ~800cy)
//   GEMM1 (u@B via bF regs, 8 MFMA)
//   [bFn = B(ct+1) + x(ct+1) issued BEFORE the barrier -> in flight across]
//   epilogue: xn = acc1 + dv*x (scalar stores, measured-ideal pattern);
//             X[ct&1] <- bf16 (swz LDS)
//   __syncthreads  (single barrier: X visible; dbuf makes WAR safe --
//     GEMM2(ct-1) -> bar(ct) -> epilogue(ct+1) reuses its buffer)
//   GEMM2 (X@C via cF regs, 8 MFMA)
// All frag loads batched into named regs -> 1 L2 round trip each, not 8
// serialized (v9's VGPR=40 showed the compiler was serializing issue).
// ---------------------------------------------------------------------------
__global__ __launch_bounds__(256, 4)
void rnn_fused(const float* __restrict__ u, const float* __restrict__ x,
               const float* __restrict__ decay,
               const ushort* __restrict__ bhi, const ushort* __restrict__ chi,
               float* __restrict__ xn, float* __restrict__ out)
{
    __shared__ __align__(16) char smem[16384];
    ushort* Ah = (ushort*)smem;             // [32][128] bf16, swz, 8KB

    const int t = threadIdx.x;
    const int lane = t & 63, wc = t >> 6;
    const int cl = lane & 15, hk = lane >> 4;
    const int row0 = blockIdx.x * ROWS;

    {   // stage A: u[32][128] f32 -> bf16 swizzled; 64B/thread coalesced
        const int r = t >> 3;
        const int kb = (t & 7) * 2;
#pragma unroll
        for (int i = 0; i < 2; ++i) {
            const float* src = u + (size_t)(row0 + r) * DIN + (kb + i) * 8;
            f32x4 v0 = *(const f32x4*)src;
            f32x4 v1 = *(const f32x4*)(src + 4);
            const int byte = (r * 256 + (kb + i) * 16) ^ ((r & 7) << 4);
            *(s16x8*)((char*)Ah + byte) = cvt8(v0, v1);
        }
    }

    // prologue: bF = B(0) frags; xv = x(0); dvc = decay(0)   (batched issue)
    s16x8 bF[4], bFn[4];
#pragma unroll
    for (int ks = 0; ks < 4; ++ks)
        bF[ks] = *(const s16x8*)(bhi + (size_t)(wc * 4 + ks) * 512 + lane * 8);

    float xv[2][4], xvn[2][4], dvc, dvn;
    dvc = decay[wc * 16 + cl];
#pragma unroll
    for (int mf = 0; mf < 2; ++mf)
#pragma unroll
        for (int j = 0; j < 4; ++j)
            xv[mf][j] = x[(size_t)(row0 + mf * 16 + 4 * hk + j) * DH + wc * 16 + cl];

    __syncthreads();   // A visible

    f32x4 acc2[2][2];
#pragma unroll
    for (int mf = 0; mf < 2; ++mf)
#pragma unroll
        for (int nf = 0; nf < 2; ++nf)
            acc2[mf][nf] = (f32x4){0.f, 0.f, 0.f, 0.f};

    for (int ct = 0; ct < 8; ++ct) {
        char* Xh = smem + 8192 + (ct & 1) * 4096;   // [32][64] bf16, swz

        // ---- issue C(ct) frag loads FIRST (consumed at chunk end)
        s16x8 cF[2][2];
#pragma unroll
        for (int ks2 = 0; ks2 < 2; ++ks2)
#pragma unroll
            for (int nf = 0; nf < 2; ++nf)
                cF[ks2][nf] = *(const s16x8*)(chi +
                    (size_t)((wc * 2 + nf) * 16 + ct * 2 + ks2) * 512 + lane * 8);

        // ---- GEMM1: acc1 = u @ B-chunk from bF regs (LDS A + MFMA only)
        f32x4 acc1[2];
        acc1[0] = (f32x4){0.f, 0.f, 0.f, 0.f};
        acc1[1] = (f32x4){0.f, 0.f, 0.f, 0.f};
#pragma unroll
        for (int ks = 0; ks < 4; ++ks) {
            const int ko = ks * 32 + hk * 8;
            s16x8 ah[2];
#pragma unroll
            for (int mf = 0; mf < 2; ++mf) {
                const int r = mf * 16 + cl;
                const int byte = (r * 256 + ko * 2) ^ ((r & 7) << 4);
                ah[mf] = *(const s16x8*)((const char*)Ah + byte);
            }
#pragma unroll
            for (int mf = 0; mf < 2; ++mf) acc1[mf] = mfma16(ah[mf], bF[ks], acc1[mf]);
        }

        // ---- issue B(ct+1) + x(ct+1) BEFORE the barrier (in flight across)
        if (ct < 7) {
#pragma unroll
            for (int ks = 0; ks < 4; ++ks)
                bFn[ks] = *(const s16x8*)(bhi +
                    (size_t)(((ct + 1) * 4 + wc) * 4 + ks) * 512 + lane * 8);
            const int ncol = (ct + 1) * 64 + wc * 16 + cl;
            dvn = decay[ncol];
#pragma unroll
            for (int mf = 0; mf < 2; ++mf)
#pragma unroll
                for (int j = 0; j < 4; ++j)
                    xvn[mf][j] = x[(size_t)(row0 + mf * 16 + 4 * hk + j) * DH + ncol];
        }

        // ---- epilogue: xn = acc1 + dv*x; X[ct&1] <- bf16 (swz LDS)
        {
            const int col = ct * 64 + wc * 16 + cl;
#pragma unroll
            for (int mf = 0; mf < 2; ++mf) {
#pragma unroll
                for (int j = 0; j < 4; ++j) {
                    const int rl = mf * 16 + 4 * hk + j;
                    const float v = acc1[mf][j] + dvc * xv[mf][j];
                    xn[(size_t)(row0 + rl) * DH + col] = v;
                    const int cbyte = (rl * 128 + (wc * 16 + cl) * 2) ^ ((rl & 7) << 4);
                    *(ushort*)(Xh + cbyte) = f32_to_bf16_rn(v);
                }
            }
        }

        __syncthreads();   // single barrier: X[ct&1] visible to all waves

        // ---- GEMM2: acc2 += X @ C-chunk from cF regs
#pragma unroll
        for (int ks2 = 0; ks2 < 2; ++ks2) {
            const int ko = ks2 * 32 + hk * 8;
            s16x8 ah2[2];
#pragma unroll
            for (int mf = 0; mf < 2; ++mf) {
                const int r = mf * 16 + cl;
                const int byte = (r * 128 + ko * 2) ^ ((r & 7) << 4);
                ah2[mf] = *(const s16x8*)((const char*)Xh + byte);
            }
#pragma unroll
            for (int nf = 0; nf < 2; ++nf)
#pragma unroll
                for (int mf = 0; mf < 2; ++mf)
                    acc2[mf][nf] = mfma16(ah2[mf], cF[ks2][nf], acc2[mf][nf]);
        }

        // ---- rotate prefetched state
#pragma unroll
        for (int ks = 0; ks < 4; ++ks) bF[ks] = bFn[ks];
        dvc = dvn;
#pragma unroll
        for (int mf = 0; mf < 2; ++mf)
#pragma unroll
            for (int j = 0; j < 4; ++j) xv[mf][j] = xvn[mf][j];
    }

    // ---- final: store out[32 x 128]; wave covers cols [wc*32, +32)
#pragma unroll
    for (int nf = 0; nf < 2; ++nf) {
        const int ocol = wc * 32 + nf * 16 + cl;
#pragma unroll
        for (int mf = 0; mf < 2; ++mf) {
#pragma unroll
            for (int j = 0; j < 4; ++j) {
                const int rl = mf * 16 + 4 * hk + j;
                out[(size_t)(row0 + rl) * DOUT + ocol] = acc2[mf][nf][j];
            }
        }
    }
}

extern "C" void kernel_launch(void* const* d_in, const int* in_sizes, int n_in,
                              void* d_out, int out_size, void* d_ws, size_t ws_size,
                              hipStream_t stream)
{
    const float* x = (const float*)d_in[0];
    const float* u = (const float*)d_in[1];
    const float* a = (const float*)d_in[2];
    const float* b = (const float*)d_in[3];
    const float* c = (const float*)d_in[4];

    float* xn  = (float*)d_out;                       // [BATCH][DH]
    float* out = xn + (size_t)BATCH * DH;             // [BATCH][DOUT]

    char* ws = (char*)d_ws;
    float*  decay = (float*)ws;                       // 512 f32
    ushort* bhi = (ushort*)(ws + 4096);               // 128KB frag-linear B
    ushort* chi = bhi + 128 * 512;                    // 128KB frag-linear C

    prep_kernel<<<dim3(65), dim3(256), 0, stream>>>(a, b, c, decay, bhi, chi);
    rnn_fused<<<dim3(BATCH / ROWS), dim3(256), 0, stream>>>(u, x, decay, bhi, chi, xn, out);
}